// Round 15
// baseline (379.245 us; speedup 1.0000x reference)
//
#include <hip/hip_runtime.h>
#include <hip/hip_bf16.h>
#include <stdint.h>

#define DIN 4096
#define DOUT 4096
#define NK 128   // 32-wide k-steps

typedef __attribute__((ext_vector_type(8))) short short8;
typedef __attribute__((ext_vector_type(8))) unsigned short ushort8;
typedef __attribute__((ext_vector_type(16))) float f32x16;

__device__ inline unsigned short f2bf(float f) {
    union { float f; unsigned u; } v; v.f = f;
    unsigned r = v.u + 0x7fffu + ((v.u >> 16) & 1u);   // RNE
    return (unsigned short)(r >> 16);
}

// ============ blocked workspace layout (h-major, r13-verified) ==============
// elem offset for (R=row/256, slice v=0..127, mt=row%256/32, s=kslice, h, r32):
//   R*1048576 + v*8192 + mt*1024 + s*512 + h*256 + r32*8
// A fragment (mt,s) of slice v = contiguous lane-ordered 1KB -> loadable
// DIRECTLY global->VGPR as one dwordx4/lane (this round's key move).

// ---- prep 1: x (f32) -> blocked bf16 (r13-verified) -------------------------
__global__ void cvt_x_blocked(const float* __restrict__ x, ushort* __restrict__ xb) {
    const int t = threadIdx.x;                 // 256
    const int bx = blockIdx.x;                 // (M/256)*64
    const int R = bx >> 6, u = bx & 63;
    const int r32 = t >> 3, kcol = t & 7;
    const int kk = kcol >> 2, s = (kcol >> 1) & 1, h = kcol & 1;
    const float* src = x + ((size_t)R * 256) * DIN + u * 64 + kcol * 8;
    ushort* dst = xb + (size_t)R * 1048576 + (size_t)u * 16384
                + (size_t)kk * 8192 + s * 512 + h * 256 + r32 * 8;
#pragma unroll
    for (int j = 0; j < 8; ++j) {
        const float* p = src + ((size_t)(j * 32 + r32)) * DIN;
        float4 v0 = *(const float4*)p, v1 = *(const float4*)(p + 4);
        ushort8 o;
        o[0] = f2bf(v0.x); o[1] = f2bf(v0.y); o[2] = f2bf(v0.z); o[3] = f2bf(v0.w);
        o[4] = f2bf(v1.x); o[5] = f2bf(v1.y); o[6] = f2bf(v1.z); o[7] = f2bf(v1.w);
        *(ushort8*)(dst + (size_t)j * 1024) = o;
    }
}

// ---- prep 2a: Wt[e][d] = bf16(base[d][e] + c*mask[d][e]) (verified) ---------
__global__ void make_wt_kernel(const float* __restrict__ base, const int* __restrict__ mask,
                               const float* __restrict__ coeff, ushort* __restrict__ wt) {
    __shared__ float tile[64][65];
    const float c = coeff[0];
    const int t = threadIdx.x;
    const int bd = blockIdx.x >> 6;
    const int be = blockIdx.x & 63;
    const int d0 = bd * 64, e0 = be * 64;
#pragma unroll
    for (int i = 0; i < 4; ++i) {
        int idx = i * 256 + t;
        int r = idx >> 4;
        int c4 = (idx & 15) << 2;
        const float4 bv = *(const float4*)(base + (size_t)(d0 + r) * DOUT + e0 + c4);
        const int4  mv = *(const int4*)(mask + (size_t)(d0 + r) * DOUT + e0 + c4);
        tile[r][c4 + 0] = bv.x + c * (float)mv.x;
        tile[r][c4 + 1] = bv.y + c * (float)mv.y;
        tile[r][c4 + 2] = bv.z + c * (float)mv.z;
        tile[r][c4 + 3] = bv.w + c * (float)mv.w;
    }
    __syncthreads();
#pragma unroll
    for (int i = 0; i < 8; ++i) {
        int idx = i * 256 + t;
        int r = idx >> 5;
        int p = (idx & 31) << 1;
        ushort2 o;
        o.x = f2bf(tile[p][r]);
        o.y = f2bf(tile[p + 1][r]);
        *(ushort2*)(wt + (size_t)(e0 + r) * DIN + d0 + p) = o;
    }
}

// ---- prep 2b: row-major Wt -> blocked (h-major, r13-verified) ---------------
__global__ void reblock_w(const ushort* __restrict__ wt_rm, ushort* __restrict__ wb) {
    const int t = threadIdx.x;
    const int bx = blockIdx.x;
    const int R = bx >> 6, u = bx & 63;
    const int r32 = t >> 3, kcol = t & 7;
    const int kk = kcol >> 2, s = (kcol >> 1) & 1, h = kcol & 1;
    const ushort* src = wt_rm + ((size_t)R * 256) * DIN + u * 64 + kcol * 8;
    ushort* dst = wb + (size_t)R * 1048576 + (size_t)u * 16384
                + (size_t)kk * 8192 + s * 512 + h * 256 + r32 * 8;
#pragma unroll
    for (int j = 0; j < 8; ++j) {
        ushort8 o = *(const ushort8*)(src + ((size_t)(j * 32 + r32)) * DIN);
        *(ushort8*)(dst + (size_t)j * 1024) = o;
    }
}

// ---- GEMM: 256x256, A direct global->reg, B via LDS (reg-staged) ------------
// Per 32-k step v (buf P=v&1):
//   read 8 B-frags from lB[P] (conflict-free);
//   load A(v+1) frags global->regs (compiler-tracked vmcnt);
//   ds_write B(v+1) into lB[P^1] from regs loaded last step;
//   load B(v+2) global->regs;
//   16 MFMA32 on A(v) regs x B(v) frags;
//   lgkmcnt(0); s_barrier.
// Safety: buf[P^1]'s previous readers (step v-1) drained their ds_reads before
// their MFMAs and the step v-1 end barrier; our writes issue after it. B(v) in
// lB[P] was written at step v-1 and lgkm(0)-drained before that same barrier.
// NO manual vmcnt anywhere -> no counted-protocol risk; barriers never drain
// the in-flight A/B global prefetch (raw s_barrier, not __syncthreads).

#define MFMA32(D, VA, VB) D = __builtin_amdgcn_mfma_f32_32x32x16_bf16(VA, VB, D, 0, 0, 0)

#define RB(P,N,S) (*(const short8*)&lB[P][bw + (N)*1024 + (S)*512])

#define STEP(P, AC, AN, BSW, BSL, AOFF, GW, GA, GL, LOFF) \
  { \
    short8 b00=RB(P,0,0),b01=RB(P,0,1),b10=RB(P,1,0),b11=RB(P,1,1); \
    short8 b20=RB(P,2,0),b21=RB(P,2,1),b30=RB(P,3,0),b31=RB(P,3,1); \
    if (GA) { AN##0=*(const short8*)(aP+(AOFF));      AN##1=*(const short8*)(aP+(AOFF)+512); \
              AN##2=*(const short8*)(aP+(AOFF)+1024); AN##3=*(const short8*)(aP+(AOFF)+1536); } \
    if (GW) { *(short8*)&lB[1-(P)][dw] = BSW##0; *(short8*)&lB[1-(P)][dw+4096] = BSW##1; } \
    if (GL) { BSL##0 = *(const short8*)(bP+(LOFF)); BSL##1 = *(const short8*)(bP+(LOFF)+4096); } \
    __builtin_amdgcn_s_setprio(1); \
    MFMA32(c00, AC##0, b00); MFMA32(c00, AC##1, b01); \
    MFMA32(c01, AC##0, b10); MFMA32(c01, AC##1, b11); \
    MFMA32(c02, AC##0, b20); MFMA32(c02, AC##1, b21); \
    MFMA32(c03, AC##0, b30); MFMA32(c03, AC##1, b31); \
    MFMA32(c10, AC##2, b00); MFMA32(c10, AC##3, b01); \
    MFMA32(c11, AC##2, b10); MFMA32(c11, AC##3, b11); \
    MFMA32(c12, AC##2, b20); MFMA32(c12, AC##3, b21); \
    MFMA32(c13, AC##2, b30); MFMA32(c13, AC##3, b31); \
    __builtin_amdgcn_s_setprio(0); \
    asm volatile("s_waitcnt lgkmcnt(0)" ::: "memory"); \
    __builtin_amdgcn_s_barrier(); \
    __builtin_amdgcn_sched_barrier(0); \
  }

__global__ __launch_bounds__(512, 2) void gemm_kernel(const ushort* __restrict__ A,
                                                      const ushort* __restrict__ Bt,
                                                      float* __restrict__ C) {
    __shared__ __align__(16) ushort lB[2][8192];   // B only: 32 KiB

    const int tid = threadIdx.x;
    const int lane = tid & 63;
    const int wave = tid >> 6;

    const int nbn = DOUT / 256;               // 16
    const int nwg = gridDim.x;                // 512
    int bid = blockIdx.x;
    int cpx = nwg >> 3;
    int s = (bid & 7) * cpx + (bid >> 3);     // XCD-contiguous chunks
    const int m0 = (s / nbn) * 256;
    const int n0 = (s % nbn) * 256;

    const int wr = wave >> 1;                 // 0..3  (M quarter: 2 mt of 32)
    const int wc = wave & 1;                  // 0..1  (N half: 4 nt of 32)
    const int fr = lane & 31;
    const int fq = lane >> 5;

    const int bw = wc * 4096 + fq * 256 + fr * 8;   // B-frag base in region
    const int dw = tid * 8;                         // ds_write dest

    // A frag pointer: per-wave rows, lane-ordered contiguous frags in global
    const ushort* aP = A + (size_t)(m0 >> 8) * 1048576
                     + (wr * 2) * 1024 + fq * 256 + fr * 8;
    const ushort* bP = Bt + (size_t)(n0 >> 8) * 1048576 + tid * 8;

    f32x16 c00 = {}, c01 = {}, c02 = {}, c03 = {};
    f32x16 c10 = {}, c11 = {}, c12 = {}, c13 = {};
    short8 aE0, aE1, aE2, aE3, aO0, aO1, aO2, aO3;   // A(v) frags: m0s0,m0s1,m1s0,m1s1
    short8 bsE0, bsE1, bsO0, bsO1;                   // B stage regs (even/odd slices)

    // prologue: B(0)->buf0, B(1)->bsO, A(0)->aE
    {
        short8 t0 = *(const short8*)(bP);
        short8 t1 = *(const short8*)(bP + 4096);
        bsO0 = *(const short8*)(bP + 8192);
        bsO1 = *(const short8*)(bP + 8192 + 4096);
        aE0 = *(const short8*)(aP);        aE1 = *(const short8*)(aP + 512);
        aE2 = *(const short8*)(aP + 1024); aE3 = *(const short8*)(aP + 1536);
        *(short8*)&lB[0][dw] = t0;
        *(short8*)&lB[0][dw + 4096] = t1;
        asm volatile("s_waitcnt lgkmcnt(0)" ::: "memory");
        __builtin_amdgcn_s_barrier();
        __builtin_amdgcn_sched_barrier(0);
    }

    // steps: v even reads buf0 (A(v)=aE), v odd reads buf1 (aO).
    // step v: A(v+1)->other set; write B(v+1) (loaded at v-1); load B(v+2).
    for (int v = 0; v < NK; v += 2) {
        const bool g = (v < NK - 2);          // guards OOB slice accesses
        STEP(0, aE, aO, bsO, bsE, 8192, 1, 1, g, 16384)
        STEP(1, aO, aE, bsE, bsO, 16384, g, g, g, 24576)
        aP += 16384; bP += 16384;
    }

    // epilogue (verified 32x32 C/D): col=fr, row=(r&3)+8*(r>>2)+4*fq
    const int gcb = n0 + wc * 128 + fr;
    const int grb = m0 + wr * 64 + fq * 4;
#define WRT(CT, MT, NN) \
    _Pragma("unroll") \
    for (int r = 0; r < 16; ++r) { \
        int grow = grb + (MT) * 32 + (r & 3) + 8 * (r >> 2); \
        C[(size_t)grow * DOUT + gcb + (NN) * 32] = CT[r]; \
    }
    WRT(c00, 0, 0) WRT(c01, 0, 1) WRT(c02, 0, 2) WRT(c03, 0, 3)
    WRT(c10, 1, 0) WRT(c11, 1, 1) WRT(c12, 1, 2) WRT(c13, 1, 3)
#undef WRT
}

extern "C" void kernel_launch(void* const* d_in, const int* in_sizes, int n_in,
                              void* d_out, int out_size, void* d_ws, size_t ws_size,
                              hipStream_t stream) {
    const float* x = (const float*)d_in[0];
    const float* base = (const float*)d_in[1];
    const float* coeff = (const float*)d_in[2];
    const int* mask = (const int*)d_in[3];
    float* out = (float*)d_out;

    const int M = in_sizes[0] / DIN;           // 8192
    ushort* xb = (ushort*)d_ws;                // M*DIN bf16 blocked (64 MB)
    ushort* wb = xb + (size_t)M * DIN;         // DOUT*DIN bf16 blocked (32 MB)
    ushort* wt_rm = (ushort*)d_out;            // scratch: row-major Wt (32 MB),
                                               // fully overwritten by gemm later

    cvt_x_blocked<<<(M / 256) * 64, 256, 0, stream>>>(x, xb);
    make_wt_kernel<<<(DIN / 64) * (DOUT / 64), 256, 0, stream>>>(base, mask, coeff, wt_rm);
    reblock_w<<<(DOUT / 256) * 64, 256, 0, stream>>>(wt_rm, wb);

    const int nwg = (M / 256) * (DOUT / 256);  // 512
    gemm_kernel<<<nwg, 512, 0, stream>>>(xb, wb, out);
}